// Round 5
// baseline (1366.714 us; speedup 1.0000x reference)
//
#include <hip/hip_runtime.h>

typedef unsigned short u16;
typedef unsigned int   u32;
typedef unsigned long long u64;
typedef __attribute__((ext_vector_type(8))) short bf16x8;
typedef __attribute__((ext_vector_type(4))) float f32x4;

#define GK 768            // K dim of all GEMMs
#define NSTEP 196
#define NWG 96            // recurrence workgroups
#define CPW 8             // channels per recurrence wg (96*8 = 768)
#define RROWS 24          // 3 gates * CPW
#define HSTEP 49152       // 64*768 elements per step slab
#define FREP 128          // flag region stride (ints) -> 512B, one region/wave

__device__ __forceinline__ u16 f2bf(float f) {
    u32 u = __float_as_uint(f);
    u = (u + 0x7fffu + ((u >> 16) & 1u)) >> 16;
    return (u16)u;
}
__device__ __forceinline__ float bf2f(u16 h) { return __uint_as_float(((u32)h) << 16); }

// ---------------------------------------------------------------------------
// fp32 -> bf16 convert for x, Wx, Wp; block 0 also zeros the flag regions
// ---------------------------------------------------------------------------
__global__ __launch_bounds__(256) void cvt_kernel(
    const float4* __restrict__ x, const float4* __restrict__ wx,
    const float4* __restrict__ wp,
    u32* __restrict__ xb, u32* __restrict__ wxb, u32* __restrict__ wpb,
    int* __restrict__ flags)
{
    const int N1 = 9633792 / 4, N2 = 1769472 / 4;
    int i = blockIdx.x * 256 + threadIdx.x;
    if (blockIdx.x == 0) {
#pragma unroll
        for (int k = 0; k < 4; ++k) flags[threadIdx.x + 256 * k] = 0;  // 8*FREP ints
    }
    const float4* src; u32* dst; int off;
    if (i < N1)            { src = x;  dst = xb;  off = i; }
    else if (i < N1 + N2)  { src = wx; dst = wxb; off = i - N1; }
    else                   { src = wp; dst = wpb; off = i - N1 - N2; }
    float4 v = src[off];
    u32 lo = (u32)f2bf(v.x) | ((u32)f2bf(v.y) << 16);
    u32 hi = (u32)f2bf(v.z) | ((u32)f2bf(v.w) << 16);
    dst[(size_t)off * 2]     = lo;
    dst[(size_t)off * 2 + 1] = hi;
}

// ---------------------------------------------------------------------------
// GEMM: out[M][N] = A[M][K] @ B[N][K]^T   (A,B bf16 row-major K-contiguous)
// MODE 1: += bias[col], bf16 out remapped to [n][b][col] with m = b*196+n
// MODE 0: fp32 out; A rows are m = n*64+b, output row remapped to b*196+n
// ---------------------------------------------------------------------------
template<int MODE>
__global__ __launch_bounds__(256) void gemm_bt(
    const u16* __restrict__ A, const u16* __restrict__ B,
    const float* __restrict__ bias, void* __restrict__ outv)
{
    __shared__ u16 As[128 * 40];
    __shared__ u16 Bs[128 * 40];
    const int tid  = threadIdx.x;
    const int lane = tid & 63;
    const int wv   = tid >> 6;
    const int m0 = blockIdx.y * 128;
    const int n0 = blockIdx.x * 128;
    const int wm = (wv & 1) * 64;
    const int wn = (wv >> 1) * 64;

    f32x4 acc[4][4];
#pragma unroll
    for (int i = 0; i < 4; ++i)
#pragma unroll
        for (int j = 0; j < 4; ++j) acc[i][j] = (f32x4){0.f, 0.f, 0.f, 0.f};

    const int r0 = tid >> 2, q0 = tid & 3;
    const u16* gA0 = A + (size_t)(m0 + r0)      * GK + q0 * 8;
    const u16* gA1 = A + (size_t)(m0 + r0 + 64) * GK + q0 * 8;
    const u16* gB0 = B + (size_t)(n0 + r0)      * GK + q0 * 8;
    const u16* gB1 = B + (size_t)(n0 + r0 + 64) * GK + q0 * 8;
    u16* sA0 = As + r0 * 40 + q0 * 8;
    u16* sA1 = As + (r0 + 64) * 40 + q0 * 8;
    u16* sB0 = Bs + r0 * 40 + q0 * 8;
    u16* sB1 = Bs + (r0 + 64) * 40 + q0 * 8;

    const int fr = lane & 15, fq = lane >> 4;
    const u16* fA = As + (wm + fr) * 40 + fq * 8;
    const u16* fB = Bs + (wn + fr) * 40 + fq * 8;

    for (int kt = 0; kt < GK / 32; ++kt) {
        uint4 a0 = *(const uint4*)(gA0 + kt * 32);
        uint4 a1 = *(const uint4*)(gA1 + kt * 32);
        uint4 b0 = *(const uint4*)(gB0 + kt * 32);
        uint4 b1 = *(const uint4*)(gB1 + kt * 32);
        __syncthreads();
        *(uint4*)sA0 = a0; *(uint4*)sA1 = a1;
        *(uint4*)sB0 = b0; *(uint4*)sB1 = b1;
        __syncthreads();
        bf16x8 af[4], bfr[4];
#pragma unroll
        for (int mi = 0; mi < 4; ++mi) af[mi]  = *(const bf16x8*)(fA + mi * 16 * 40);
#pragma unroll
        for (int ni = 0; ni < 4; ++ni) bfr[ni] = *(const bf16x8*)(fB + ni * 16 * 40);
#pragma unroll
        for (int mi = 0; mi < 4; ++mi)
#pragma unroll
            for (int ni = 0; ni < 4; ++ni)
                acc[mi][ni] = __builtin_amdgcn_mfma_f32_16x16x32_bf16(
                    af[mi], bfr[ni], acc[mi][ni], 0, 0, 0);
    }

    if (MODE == 1) {
        u16* out = (u16*)outv;
#pragma unroll
        for (int mi = 0; mi < 4; ++mi) {
#pragma unroll
            for (int ni = 0; ni < 4; ++ni) {
                int col = n0 + wn + ni * 16 + fr;
                float bv = bias[col];
#pragma unroll
                for (int r = 0; r < 4; ++r) {
                    int m = m0 + wm + mi * 16 + fq * 4 + r;
                    int b = m / 196;
                    int nn = m - b * 196;
                    u16 hv = f2bf(acc[mi][ni][r] + bv);
                    int other = __shfl_xor((int)hv, 1, 64);
                    if (!(lane & 1)) {
                        u32 packed = (u32)hv | (((u32)(u16)other) << 16);
                        size_t eidx = ((size_t)nn * 64 + (size_t)b) * 2304 + (size_t)col;
                        *((u32*)out + (eidx >> 1)) = packed;
                    }
                }
            }
        }
    } else {
        float* out = (float*)outv;
#pragma unroll
        for (int mi = 0; mi < 4; ++mi) {
#pragma unroll
            for (int ni = 0; ni < 4; ++ni) {
                int col = n0 + wn + ni * 16 + fr;
#pragma unroll
                for (int r = 0; r < 4; ++r) {
                    int m = m0 + wm + mi * 16 + fq * 4 + r;   // m = n*64 + b
                    int b = m & 63;
                    int nn = m >> 6;
                    out[((size_t)b * 196 + nn) * 768 + col] = acc[mi][ni][r];
                }
            }
        }
    }
}

// ---------------------------------------------------------------------------
// Persistent cooperative GRU recurrence.
// 96 wgs x 512 threads (8 waves = 4 batch-tiles x 2 K-halves).
// Wh slice (24 rows) lives in REGISTERS as MFMA B-frags.
// h exchange: rotating slab hsx[n][64][768]; producers publish via 8B
// write-through agent stores; readers use normal cached dwordx4 loads.
// Barrier: REPLICATED per-wg monotonic flags -- 8 regions (512B apart),
// one per wave slot. Wave wv polls only region wv (96 pollers/line instead
// of 768), and lane 0 of wave wv publishes its wg's flag into region wv
// after the drain barrier (8 parallel stores to distinct lines).
// Poll is software-pipelined: next load-pair in flight while testing prev.
// ---------------------------------------------------------------------------
__global__ __launch_bounds__(512) void recur_kernel(
    const u16* __restrict__ xz,   // [196][64][2304] bf16 (x proj + bx)
    const float* __restrict__ Wh, // [2304][768] f32
    const float* __restrict__ bh, // [2304] f32
    u16* __restrict__ hsx,        // [196][64][768] bf16 (exchange + output)
    int* flags)                   // [8][FREP] replicated flags (pre-zeroed)
{
    __shared__ float hz_s[2][64 * 28];   // partial h_zrn per K-half, [b][24 pad 28]
    __shared__ float hold_s[512];        // previous h for own channels [b][8]

    const int tid  = threadIdx.x;
    const int wg   = blockIdx.x;
    const int c0   = wg * CPW;
    const int lane = tid & 63;
    const int wv   = tid >> 6;
    const int mi   = wv & 3;     // batch tile (16 batches)
    const int kh   = wv >> 2;    // K half (384 each)
    const int fr   = lane & 15, fq = lane >> 4;
    int* const freg = flags + wv * FREP;   // this wave's flag region

    // one-time: invalidate any stale (poison-era) L1/L2 lines
    __builtin_amdgcn_fence(__ATOMIC_ACQUIRE, "agent");

    // ---- one-time: Wh slice -> B-frags in registers (bf16), rows>=24 zero ----
    bf16x8 bfrag[2][12];
#pragma unroll
    for (int ni = 0; ni < 2; ++ni) {
        int row = ni * 16 + fr;
        bool valid = row < RROWS;
        int gate = row >> 3, ch = row & 7;
        const float* wp = Wh + (size_t)(valid ? (gate * 768 + c0 + ch) : 0) * 768;
#pragma unroll
        for (int kk = 0; kk < 12; ++kk) {
            int k0 = (kh * 12 + kk) * 32 + fq * 8;
            float4 f0 = *(const float4*)(wp + k0);
            float4 f1 = *(const float4*)(wp + k0 + 4);
            bf16x8 b;
            b[0] = (short)f2bf(f0.x); b[1] = (short)f2bf(f0.y);
            b[2] = (short)f2bf(f0.z); b[3] = (short)f2bf(f0.w);
            b[4] = (short)f2bf(f1.x); b[5] = (short)f2bf(f1.y);
            b[6] = (short)f2bf(f1.z); b[7] = (short)f2bf(f1.w);
            if (!valid) b = (bf16x8){0,0,0,0,0,0,0,0};
            bfrag[ni][kk] = b;
        }
    }

    hold_s[tid] = 0.f;
    __syncthreads();

    // gate-phase constants (one (batch,channel) per thread)
    const int gb = tid >> 3, gi = tid & 7;
    const int gc = c0 + gi;
    const float bh0 = bh[gc], bh1 = bh[768 + gc], bh2 = bh[1536 + gc];

    // A-fragment element offset within one step slab
    const int aoff = (mi * 16 + fr) * 768 + kh * 384 + fq * 8;

    for (int n = 0; n < NSTEP; ++n) {
        // prefetch x-projection for this step (independent of h)
        size_t xoff = (size_t)n * 147456 + (size_t)gb * 2304 + (size_t)gc;
        float xg0 = bf2f(xz[xoff]);
        float xg1 = bf2f(xz[xoff + 768]);
        float xg2 = bf2f(xz[xoff + 1536]);

        f32x4 acc0 = (f32x4){0.f, 0.f, 0.f, 0.f};
        f32x4 acc1 = (f32x4){0.f, 0.f, 0.f, 0.f};

        if (n > 0) {
            // poll own flag region: all 96 wgs must have published step n-1.
            // software-pipelined: next pair in flight while testing previous.
            int v0 = __hip_atomic_load(&freg[lane], __ATOMIC_RELAXED,
                                       __HIP_MEMORY_SCOPE_AGENT);
            int v1 = __hip_atomic_load(&freg[lane + 32], __ATOMIC_RELAXED,
                                       __HIP_MEMORY_SCOPE_AGENT);
            for (;;) {
                int w0 = __hip_atomic_load(&freg[lane], __ATOMIC_RELAXED,
                                           __HIP_MEMORY_SCOPE_AGENT);
                int w1 = __hip_atomic_load(&freg[lane + 32], __ATOMIC_RELAXED,
                                           __HIP_MEMORY_SCOPE_AGENT);
                if (__all(v0 >= n && v1 >= n)) break;
                v0 = w0; v1 = w1;
            }

            const u16* ap = hsx + (size_t)(n - 1) * HSTEP + aoff;
#pragma unroll
            for (int kk = 0; kk < 12; ++kk) {
                bf16x8 a = *(const bf16x8*)(ap + kk * 32);   // cached dwordx4
                acc0 = __builtin_amdgcn_mfma_f32_16x16x32_bf16(a, bfrag[0][kk], acc0, 0, 0, 0);
                acc1 = __builtin_amdgcn_mfma_f32_16x16x32_bf16(a, bfrag[1][kk], acc1, 0, 0, 0);
            }
        }

        {
            int bat = mi * 16 + fq * 4;
#pragma unroll
            for (int r = 0; r < 4; ++r)
                hz_s[kh][(bat + r) * 28 + fr] = acc0[r];
            if (fr < 8) {
#pragma unroll
                for (int r = 0; r < 4; ++r)
                    hz_s[kh][(bat + r) * 28 + 16 + fr] = acc1[r];
            }
        }
        __syncthreads();

        // gates: one (batch, channel) per thread
        float h0 = hz_s[0][gb * 28 + gi]      + hz_s[1][gb * 28 + gi]      + bh0;
        float h1 = hz_s[0][gb * 28 + 8 + gi]  + hz_s[1][gb * 28 + 8 + gi]  + bh1;
        float h2 = hz_s[0][gb * 28 + 16 + gi] + hz_s[1][gb * 28 + 16 + gi] + bh2;
        float z  = 1.f / (1.f + __expf(-(xg0 + h0)));
        float rr = 1.f / (1.f + __expf(-(xg1 + h1)));
        float pre = xg2 + rr * h2;
        float e2 = __expf(-2.f * pre);
        float nc = (1.f - e2) / (1.f + e2);
        float hold = hold_s[tid];
        float hnew = (1.f - z) * nc + z * hold;
        hold_s[tid] = hnew;

        // pack 4 channels -> one 8B write-through store per 4 threads
        u16 hv = f2bf(hnew);
        u32 other = ((u32)__shfl_xor((int)hv, 1, 64)) & 0xffffu;
        u32 v01 = (u32)hv | (other << 16);                  // valid on even gi
        u32 v23 = (u32)__shfl_xor((int)v01, 2, 64);         // pair from gi^2
        if ((tid & 3) == 0) {
            u64 q = (u64)v01 | ((u64)v23 << 32);
            size_t ofs = (size_t)n * HSTEP + (size_t)gb * 768 + (size_t)gc;
            __hip_atomic_store((u64*)((u32*)hsx + (ofs >> 1)), q,
                               __ATOMIC_RELAXED, __HIP_MEMORY_SCOPE_AGENT);
        }
        __syncthreads();   // all waves drain vmcnt before flag publish
        // each wave's lane 0 publishes this wg's flag into its own region
        if (lane == 0)
            __hip_atomic_store(&freg[wg], n + 1, __ATOMIC_RELAXED,
                               __HIP_MEMORY_SCOPE_AGENT);
    }
}

// ---------------------------------------------------------------------------
extern "C" void kernel_launch(void* const* d_in, const int* in_sizes, int n_in,
                              void* d_out, int out_size, void* d_ws, size_t ws_size,
                              hipStream_t stream)
{
    const float* x  = (const float*)d_in[0];
    const float* Wx = (const float*)d_in[1];
    const float* bx = (const float*)d_in[2];
    const float* Wh = (const float*)d_in[3];
    const float* bh = (const float*)d_in[4];
    const float* Wp = (const float*)d_in[5];
    float* out = (float*)d_out;

    char* ws = (char*)d_ws;
    size_t off = 0;
    auto wsalloc = [&](size_t bytes) -> void* {
        void* p = ws + off;
        off += (bytes + 255) & ~(size_t)255;
        return p;
    };
    u16* xb   = (u16*)wsalloc(9633792ull * 2);            // x bf16 [12544][768]
    u16* wxb  = (u16*)wsalloc(1769472ull * 2);            // Wx bf16 [2304][768]
    u16* wpb  = (u16*)wsalloc(589824ull * 2);             // Wp bf16 [768][768]
    u16* xzrn = (u16*)wsalloc(196ull * 64 * 2304 * 2);    // [n][b][3C] bf16
    u16* hsx  = (u16*)wsalloc(196ull * 64 * 768 * 2);     // [n][b][C] bf16
    int* flags = (int*)wsalloc(8 * FREP * 4);             // replicated flags

    // 1) converts (+ zero flag regions)
    cvt_kernel<<<11712, 256, 0, stream>>>(
        (const float4*)x, (const float4*)Wx, (const float4*)Wp,
        (u32*)xb, (u32*)wxb, (u32*)wpb, flags);

    // 2) x_zrn = seq @ Wx^T + bx  ->  [n][b][3C] bf16
    gemm_bt<1><<<dim3(18, 98), 256, 0, stream>>>(xb, wxb, bx, (void*)xzrn);

    // 3) cooperative recurrence
    {
        const u16* a0 = xzrn; const float* a1 = Wh; const float* a2 = bh;
        u16* a3 = hsx; int* a4 = flags;
        void* args[5] = { &a0, &a1, &a2, &a3, &a4 };
        hipLaunchCooperativeKernel((void*)recur_kernel, dim3(NWG), dim3(512),
                                   args, 0, stream);
    }

    // 4) y = hsx @ Wp^T -> d_out fp32 (rows m = n*64+b, remapped on store)
    gemm_bt<0><<<dim3(6, 98), 256, 0, stream>>>(hsx, wpb, nullptr, (void*)out);
}

// Round 6
// 1362.894 us; speedup vs baseline: 1.0028x; 1.0028x over previous
//
#include <hip/hip_runtime.h>

typedef unsigned short u16;
typedef unsigned int   u32;
typedef unsigned long long u64;
typedef __attribute__((ext_vector_type(8))) short bf16x8;
typedef __attribute__((ext_vector_type(4))) float f32x4;

#define GK 768            // K dim of all GEMMs
#define NSTEP 196
#define HSTEP 49152       // 64*768 elements per step slab
#define NWG2 256          // launched wgs (pigeonhole: 1 per CU)
#define WPX 24            // workers per XCD
#define CPW2 32           // channels per worker
#define THR2 384          // 6 waves
#define DYNLDS 82000      // forces 1 wg/CU (needs > 160KB/2)

__device__ __forceinline__ u16 f2bf(float f) {
    u32 u = __float_as_uint(f);
    u = (u + 0x7fffu + ((u >> 16) & 1u)) >> 16;
    return (u16)u;
}
__device__ __forceinline__ float bf2f(u16 h) { return __uint_as_float(((u32)h) << 16); }

// ---------------------------------------------------------------------------
// fp32 -> bf16 convert for x, Wx, Wp; blocks 0/1 zero flags + tickets
// ---------------------------------------------------------------------------
__global__ __launch_bounds__(256) void cvt_kernel(
    const float4* __restrict__ x, const float4* __restrict__ wx,
    const float4* __restrict__ wp,
    u32* __restrict__ xb, u32* __restrict__ wxb, u32* __restrict__ wpb,
    int* __restrict__ flagmem)
{
    const int N1 = 9633792 / 4, N2 = 1769472 / 4;
    int i = blockIdx.x * 256 + threadIdx.x;
    if (blockIdx.x == 0) flagmem[threadIdx.x] = 0;                    // flags [256]
    else if (blockIdx.x == 1 && threadIdx.x < 64) flagmem[256 + threadIdx.x] = 0; // tickets
    const float4* src; u32* dst; int off;
    if (i < N1)            { src = x;  dst = xb;  off = i; }
    else if (i < N1 + N2)  { src = wx; dst = wxb; off = i - N1; }
    else                   { src = wp; dst = wpb; off = i - N1 - N2; }
    float4 v = src[off];
    u32 lo = (u32)f2bf(v.x) | ((u32)f2bf(v.y) << 16);
    u32 hi = (u32)f2bf(v.z) | ((u32)f2bf(v.w) << 16);
    dst[(size_t)off * 2]     = lo;
    dst[(size_t)off * 2 + 1] = hi;
}

// ---------------------------------------------------------------------------
// GEMM: out[M][N] = A[M][K] @ B[N][K]^T   (A,B bf16 row-major K-contiguous)
// MODE 1: += bias[col], bf16 out remapped to [n][b][col] with m = b*196+n
// MODE 0: fp32 out; A rows are m = n*64+b, output row remapped to b*196+n
// ---------------------------------------------------------------------------
template<int MODE>
__global__ __launch_bounds__(256) void gemm_bt(
    const u16* __restrict__ A, const u16* __restrict__ B,
    const float* __restrict__ bias, void* __restrict__ outv)
{
    __shared__ u16 As[128 * 40];
    __shared__ u16 Bs[128 * 40];
    const int tid  = threadIdx.x;
    const int lane = tid & 63;
    const int wv   = tid >> 6;
    const int m0 = blockIdx.y * 128;
    const int n0 = blockIdx.x * 128;
    const int wm = (wv & 1) * 64;
    const int wn = (wv >> 1) * 64;

    f32x4 acc[4][4];
#pragma unroll
    for (int i = 0; i < 4; ++i)
#pragma unroll
        for (int j = 0; j < 4; ++j) acc[i][j] = (f32x4){0.f, 0.f, 0.f, 0.f};

    const int r0 = tid >> 2, q0 = tid & 3;
    const u16* gA0 = A + (size_t)(m0 + r0)      * GK + q0 * 8;
    const u16* gA1 = A + (size_t)(m0 + r0 + 64) * GK + q0 * 8;
    const u16* gB0 = B + (size_t)(n0 + r0)      * GK + q0 * 8;
    const u16* gB1 = B + (size_t)(n0 + r0 + 64) * GK + q0 * 8;
    u16* sA0 = As + r0 * 40 + q0 * 8;
    u16* sA1 = As + (r0 + 64) * 40 + q0 * 8;
    u16* sB0 = Bs + r0 * 40 + q0 * 8;
    u16* sB1 = Bs + (r0 + 64) * 40 + q0 * 8;

    const int fr = lane & 15, fq = lane >> 4;
    const u16* fA = As + (wm + fr) * 40 + fq * 8;
    const u16* fB = Bs + (wn + fr) * 40 + fq * 8;

    for (int kt = 0; kt < GK / 32; ++kt) {
        uint4 a0 = *(const uint4*)(gA0 + kt * 32);
        uint4 a1 = *(const uint4*)(gA1 + kt * 32);
        uint4 b0 = *(const uint4*)(gB0 + kt * 32);
        uint4 b1 = *(const uint4*)(gB1 + kt * 32);
        __syncthreads();
        *(uint4*)sA0 = a0; *(uint4*)sA1 = a1;
        *(uint4*)sB0 = b0; *(uint4*)sB1 = b1;
        __syncthreads();
        bf16x8 af[4], bfr[4];
#pragma unroll
        for (int mi = 0; mi < 4; ++mi) af[mi]  = *(const bf16x8*)(fA + mi * 16 * 40);
#pragma unroll
        for (int ni = 0; ni < 4; ++ni) bfr[ni] = *(const bf16x8*)(fB + ni * 16 * 40);
#pragma unroll
        for (int mi = 0; mi < 4; ++mi)
#pragma unroll
            for (int ni = 0; ni < 4; ++ni)
                acc[mi][ni] = __builtin_amdgcn_mfma_f32_16x16x32_bf16(
                    af[mi], bfr[ni], acc[mi][ni], 0, 0, 0);
    }

    if (MODE == 1) {
        u16* out = (u16*)outv;
#pragma unroll
        for (int mi = 0; mi < 4; ++mi) {
#pragma unroll
            for (int ni = 0; ni < 4; ++ni) {
                int col = n0 + wn + ni * 16 + fr;
                float bv = bias[col];
#pragma unroll
                for (int r = 0; r < 4; ++r) {
                    int m = m0 + wm + mi * 16 + fq * 4 + r;
                    int b = m / 196;
                    int nn = m - b * 196;
                    u16 hv = f2bf(acc[mi][ni][r] + bv);
                    int other = __shfl_xor((int)hv, 1, 64);
                    if (!(lane & 1)) {
                        u32 packed = (u32)hv | (((u32)(u16)other) << 16);
                        size_t eidx = ((size_t)nn * 64 + (size_t)b) * 2304 + (size_t)col;
                        *((u32*)out + (eidx >> 1)) = packed;
                    }
                }
            }
        }
    } else {
        float* out = (float*)outv;
#pragma unroll
        for (int mi = 0; mi < 4; ++mi) {
#pragma unroll
            for (int ni = 0; ni < 4; ++ni) {
                int col = n0 + wn + ni * 16 + fr;
#pragma unroll
                for (int r = 0; r < 4; ++r) {
                    int m = m0 + wm + mi * 16 + fq * 4 + r;   // m = n*64 + b
                    int b = m & 63;
                    int nn = m >> 6;
                    out[((size_t)b * 196 + nn) * 768 + col] = acc[mi][ni][r];
                }
            }
        }
    }
}

// ---------------------------------------------------------------------------
// XCD-local persistent GRU recurrence.
// 256 wgs x 384 threads, 82KB dynamic LDS -> exactly 1 wg/CU -> exactly
// 32 wgs per XCD (pigeonhole). Each wg reads its physical XCD id
// (s_getreg HW_REG_XCC_ID, id=20 size=4), claims a per-XCD slot via ticket;
// slots 0..23 work (32 channels each, 8 batches = group = XCD), rest exit.
// Wh slice (96 rows x 768) lives in REGISTERS (24 bf16x8 frags/lane).
// h exchange: rotating slab hsx[n], NORMAL cached stores/loads -- producer
// and consumers share the same XCD L2 (coherence point for the group);
// fresh addresses each step so L1 can never be stale. Flags via agent-scope
// atomics (L3), published after the __syncthreads vmcnt drain.
// ---------------------------------------------------------------------------
__global__ __launch_bounds__(THR2) void recur2_kernel(
    const u16* __restrict__ xz,   // [196][64][2304] bf16 (x proj + bx)
    const float* __restrict__ Wh, // [2304][768] f32
    const float* __restrict__ bh, // [2304] f32
    u16* __restrict__ hsx,        // [196][64][768] bf16 (exchange + output)
    int* flagmem)                 // [256] flags, [8] tickets at +256
{
    extern __shared__ char smem[];
    float* hz = (float*)smem;             // [96 rows][8 batches] f32
    int*   mb = (int*)(smem + 3200);

    const int tid = threadIdx.x;
    int* flags   = flagmem;
    int* tickets = flagmem + 256;

    if (tid == 0) {
        int x = __builtin_amdgcn_s_getreg(6164) & 7;   // HW_REG_XCC_ID, 4 bits
        int s = __hip_atomic_fetch_add(&tickets[x], 1, __ATOMIC_RELAXED,
                                       __HIP_MEMORY_SCOPE_AGENT);
        mb[0] = x; mb[1] = s;
    }
    __syncthreads();
    const int xcd = mb[0], slot = mb[1];
    if (slot >= WPX) return;              // uniform per wg

    const int lane = tid & 63;
    const int wv   = tid >> 6;            // 0..5: row-tile of the 96-row slice
    const int fr   = lane & 15, fq = lane >> 4;
    const int c0   = slot * CPW2;

    // ---- Wh slice -> B-frags in registers (rows R=wv*16+fr, all valid) ----
    bf16x8 bfrag[24];
    {
        int R = wv * 16 + fr;
        int gate = R >> 5, ch = R & 31;
        const float* wp = Wh + (size_t)(gate * 768 + c0 + ch) * 768 + fq * 8;
#pragma unroll
        for (int kk = 0; kk < 24; ++kk) {
            float4 f0 = *(const float4*)(wp + kk * 32);
            float4 f1 = *(const float4*)(wp + kk * 32 + 4);
            bf16x8 b;
            b[0] = (short)f2bf(f0.x); b[1] = (short)f2bf(f0.y);
            b[2] = (short)f2bf(f0.z); b[3] = (short)f2bf(f0.w);
            b[4] = (short)f2bf(f1.x); b[5] = (short)f2bf(f1.y);
            b[6] = (short)f2bf(f1.z); b[7] = (short)f2bf(f1.w);
            bfrag[kk] = b;
        }
    }

    // gate-phase constants (one (batch,channel) per thread, tid<256)
    int gbatch = 0, gc = 0;
    float bh0 = 0.f, bh1 = 0.f, bh2 = 0.f;
    const int gb = (tid >> 5) & 7, gch = tid & 31;
    if (tid < 256) {
        gc = c0 + gch;
        gbatch = xcd * 8 + gb;
        bh0 = bh[gc]; bh1 = bh[768 + gc]; bh2 = bh[1536 + gc];
    }
    float hold = 0.f;

    // A-fragment element offset within one step slab (batch = xcd*8 + fr&7)
    const int aoff = (xcd * 8 + (fr & 7)) * 768 + fq * 8;

    for (int n = 0; n < NSTEP; ++n) {
        // prefetch x-projection for this step (independent of h)
        float xg0 = 0.f, xg1 = 0.f, xg2 = 0.f;
        if (tid < 256) {
            size_t xoff = (size_t)n * 147456 + (size_t)gbatch * 2304 + (size_t)gc;
            xg0 = bf2f(xz[xoff]);
            xg1 = bf2f(xz[xoff + 768]);
            xg2 = bf2f(xz[xoff + 1536]);
        }

        f32x4 accA = (f32x4){0.f, 0.f, 0.f, 0.f};
        f32x4 accB = (f32x4){0.f, 0.f, 0.f, 0.f};

        if (n > 0) {
            // poll this XCD's 24 worker flags (agent atomics, L3)
            int* fl = flags + xcd * 32;
            for (;;) {
                int v = 0x7fffffff;
                if (lane < WPX)
                    v = __hip_atomic_load(&fl[lane], __ATOMIC_RELAXED,
                                          __HIP_MEMORY_SCOPE_AGENT);
                if (__all(v >= n)) break;
            }

            // h from own-XCD L2, normal cached 16B loads; MFMA K=768 in 2 chains
            const u16* ap = hsx + (size_t)(n - 1) * HSTEP + aoff;
#pragma unroll
            for (int kk = 0; kk < 12; ++kk) {
                union { uint4 u; bf16x8 v; } a0, a1;
                a0.u = *(const uint4*)(ap + kk * 32);
                a1.u = *(const uint4*)(ap + (kk + 12) * 32);
                accA = __builtin_amdgcn_mfma_f32_16x16x32_bf16(a0.v, bfrag[kk], accA, 0, 0, 0);
                accB = __builtin_amdgcn_mfma_f32_16x16x32_bf16(a1.v, bfrag[kk + 12], accB, 0, 0, 0);
            }
        }

        // C-frag: col(lane&15)=Wh-row-in-tile, row(fq*4+r)=batch (valid 0..7)
        if (fq < 2) {
#pragma unroll
            for (int r = 0; r < 4; ++r)
                hz[(wv * 16 + fr) * 8 + fq * 4 + r] = accA[r] + accB[r];
        }
        __syncthreads();

        // gates: one (batch, channel) per thread
        if (tid < 256) {
            float h0 = hz[gch * 8 + gb]        + bh0;
            float h1 = hz[(32 + gch) * 8 + gb] + bh1;
            float h2 = hz[(64 + gch) * 8 + gb] + bh2;
            float z  = 1.f / (1.f + __expf(-(xg0 + h0)));
            float rr = 1.f / (1.f + __expf(-(xg1 + h1)));
            float pre = xg2 + rr * h2;
            float e2 = __expf(-2.f * pre);
            float nc = (1.f - e2) / (1.f + e2);
            float hnew = (1.f - z) * nc + z * hold;
            hold = hnew;

            // pack 8 channels -> one full-16B normal store per 8 threads
            u16 hv = f2bf(hnew);
            u32 p  = (u32)hv | (((u32)__shfl_xor((int)hv, 1, 64) & 0xffffu) << 16);
            u32 q  = (u32)__shfl_xor((int)p, 2, 64);
            u32 r0 = (u32)__shfl_xor((int)p, 4, 64);
            u32 r1 = (u32)__shfl_xor((int)q, 4, 64);
            if ((gch & 7) == 0) {
                uint4 val; val.x = p; val.y = q; val.z = r0; val.w = r1;
                *(uint4*)(hsx + (size_t)n * HSTEP + (size_t)gbatch * 768 + gc) = val;
            }
        }
        __syncthreads();   // drains each wave's vmcnt (stores in L2) before flag
        if (tid == 0)
            __hip_atomic_store(&flags[xcd * 32 + slot], n + 1, __ATOMIC_RELAXED,
                               __HIP_MEMORY_SCOPE_AGENT);
    }
}

// ---------------------------------------------------------------------------
extern "C" void kernel_launch(void* const* d_in, const int* in_sizes, int n_in,
                              void* d_out, int out_size, void* d_ws, size_t ws_size,
                              hipStream_t stream)
{
    const float* x  = (const float*)d_in[0];
    const float* Wx = (const float*)d_in[1];
    const float* bx = (const float*)d_in[2];
    const float* Wh = (const float*)d_in[3];
    const float* bh = (const float*)d_in[4];
    const float* Wp = (const float*)d_in[5];
    float* out = (float*)d_out;

    char* ws = (char*)d_ws;
    size_t off = 0;
    auto wsalloc = [&](size_t bytes) -> void* {
        void* p = ws + off;
        off += (bytes + 255) & ~(size_t)255;
        return p;
    };
    u16* xb   = (u16*)wsalloc(9633792ull * 2);            // x bf16 [12544][768]
    u16* wxb  = (u16*)wsalloc(1769472ull * 2);            // Wx bf16 [2304][768]
    u16* wpb  = (u16*)wsalloc(589824ull * 2);             // Wp bf16 [768][768]
    u16* xzrn = (u16*)wsalloc(196ull * 64 * 2304 * 2);    // [n][b][3C] bf16
    u16* hsx  = (u16*)wsalloc(196ull * 64 * 768 * 2);     // [n][b][C] bf16
    int* flagmem = (int*)wsalloc(320 * 4);                // flags[256]+tickets[8]

    // allow >64KB dynamic LDS (idempotent, host-side, capture-safe)
    (void)hipFuncSetAttribute((const void*)recur2_kernel,
                              hipFuncAttributeMaxDynamicSharedMemorySize, 163840);

    // 1) converts (+ zero flags/tickets)
    cvt_kernel<<<11712, 256, 0, stream>>>(
        (const float4*)x, (const float4*)Wx, (const float4*)Wp,
        (u32*)xb, (u32*)wxb, (u32*)wpb, flagmem);

    // 2) x_zrn = seq @ Wx^T + bx  ->  [n][b][3C] bf16
    gemm_bt<1><<<dim3(18, 98), 256, 0, stream>>>(xb, wxb, bx, (void*)xzrn);

    // 3) XCD-local recurrence (cooperative: guarantees 256 co-resident wgs)
    {
        const u16* a0 = xzrn; const float* a1 = Wh; const float* a2 = bh;
        u16* a3 = hsx; int* a4 = flagmem;
        void* args[5] = { &a0, &a1, &a2, &a3, &a4 };
        hipLaunchCooperativeKernel((void*)recur2_kernel, dim3(NWG2), dim3(THR2),
                                   args, DYNLDS, stream);
    }

    // 4) y = hsx @ Wp^T -> d_out fp32 (rows m = n*64+b, remapped on store)
    gemm_bt<0><<<dim3(6, 98), 256, 0, stream>>>(hsx, wpb, nullptr, (void*)out);
}